// Round 1
// baseline (63796.802 us; speedup 1.0000x reference)
//
#include <hip/hip_runtime.h>
#include <math.h>

#define DEV_INLINE __device__ __forceinline__

static constexpr int Bn = 64;     // batch
static constexpr int Tn = 512;    // time
static constexpr int En = 512;    // embed
static constexpr int Hn = 1024;   // hidden
static constexpr int Cn = 256;    // classes
static constexpr int Gn = 4 * Hn; // 4096 gates

DEV_INLINE float sigmoidf_(float v) { return 1.f / (1.f + __expf(-v)); }

// ---------------------------------------------------------------------------
// Packed {gen(hi32), count(lo32)} grid barrier, agent-scope, no cache flushes.
// Sound because all inter-block data (h) moves via write-through stores and
// cache-bypassing loads; the barrier only needs ordering at the coherence pt.
// ---------------------------------------------------------------------------
DEV_INLINE void grid_sync(unsigned long long* bar, unsigned nb) {
  __syncthreads();                     // also drains vmcnt -> h stores visible
  if (threadIdx.x == 0) {
    unsigned long long old =
        __hip_atomic_fetch_add(bar, 1ull, __ATOMIC_RELAXED, __HIP_MEMORY_SCOPE_AGENT);
    unsigned g = (unsigned)(old >> 32);
    if ((unsigned)(old & 0xffffffffull) == nb - 1u) {
      // last arriver: reset count and bump generation in ONE atomic store
      __hip_atomic_store(bar, ((unsigned long long)(g + 1)) << 32,
                         __ATOMIC_RELAXED, __HIP_MEMORY_SCOPE_AGENT);
    } else {
      while ((unsigned)(__hip_atomic_load(bar, __ATOMIC_RELAXED,
                                          __HIP_MEMORY_SCOPE_AGENT) >> 32) == g) {
        __builtin_amdgcn_s_sleep(2);
      }
    }
  }
  __syncthreads();
}

// ---------------------------------------------------------------------------
// Generic fp32 tiled GEMM:  C[M,N] = A[M,K] * B[N,K]^T + bias1[n] (+bias2[n])
// 64x64 tile, KC=32 chunks, 256 threads, 4x4 micro-tile per thread.
// Used for proj (embed x W_ih^T) and the final FC.
// ---------------------------------------------------------------------------
__global__ __launch_bounds__(256) void gemm_tt(
    const float* __restrict__ A, const float* __restrict__ Bm,
    const float* __restrict__ bias1, const float* __restrict__ bias2,
    float* __restrict__ Cm, int M, int N, int K)
{
  constexpr int KC = 32;
  __shared__ float As[KC][68];   // 68: 16B-aligned rows, conflict-light
  __shared__ float Bs[KC][68];
  const int tid = threadIdx.x;
  const int tx = tid & 15, ty = tid >> 4;
  const int m0 = blockIdx.x * 64, n0 = blockIdx.y * 64;

  float acc[4][4] = {};

  for (int k0 = 0; k0 < K; k0 += KC) {
    __syncthreads();
    // stage 64 rows x 32 cols of A and B (transposed into [k][row])
    #pragma unroll
    for (int j = 0; j < 2; ++j) {
      int f = tid + j * 256;       // 0..511
      int row = f >> 3;            // 0..63
      int c4 = f & 7;              // 0..7 (float4 along K)
      float4 va = *reinterpret_cast<const float4*>(&A[(size_t)(m0 + row) * K + k0 + c4 * 4]);
      As[c4 * 4 + 0][row] = va.x; As[c4 * 4 + 1][row] = va.y;
      As[c4 * 4 + 2][row] = va.z; As[c4 * 4 + 3][row] = va.w;
      float4 vb = *reinterpret_cast<const float4*>(&Bm[(size_t)(n0 + row) * K + k0 + c4 * 4]);
      Bs[c4 * 4 + 0][row] = vb.x; Bs[c4 * 4 + 1][row] = vb.y;
      Bs[c4 * 4 + 2][row] = vb.z; Bs[c4 * 4 + 3][row] = vb.w;
    }
    __syncthreads();
    #pragma unroll
    for (int k = 0; k < KC; ++k) {
      float4 a4 = *reinterpret_cast<const float4*>(&As[k][ty * 4]);
      float4 b4 = *reinterpret_cast<const float4*>(&Bs[k][tx * 4]);
      float ar[4] = {a4.x, a4.y, a4.z, a4.w};
      float br[4] = {b4.x, b4.y, b4.z, b4.w};
      #pragma unroll
      for (int i = 0; i < 4; ++i)
        #pragma unroll
        for (int j = 0; j < 4; ++j)
          acc[i][j] += ar[i] * br[j];
    }
  }

  #pragma unroll
  for (int j = 0; j < 4; ++j) {
    int n = n0 + tx * 4 + j;
    float bb = bias1[n];
    if (bias2) bb += bias2[n];
    #pragma unroll
    for (int i = 0; i < 4; ++i)
      Cm[(size_t)(m0 + ty * 4 + i) * N + n] = acc[i][j] + bb;
  }
}

// ---------------------------------------------------------------------------
// Persistent LSTM recurrence. 256 blocks x 512 threads (1 block/CU).
// Block (bg, hg): batch rows [bg*16, +16), h-cols [hg*16, +16).
// Thread: one (b, hc) pair, K split across lane-halves (lane^32 partner).
// 4 independent barrier groups (one per bg) -> 64-arriver barriers.
// hg is XCD-major so each XCD's W_hh slice (2 MB) stays L2-resident.
// ---------------------------------------------------------------------------
__global__ __launch_bounds__(512, 2) void lstm_persistent(
    const int* __restrict__ x,        // [B, T]
    const float* __restrict__ Whh,    // [4H, H]
    const float* __restrict__ proj,   // [C, 4H] class gates incl. both biases
    float* __restrict__ hs,           // [B, T, H]
    unsigned long long* __restrict__ bar)
{
  __shared__ float hsm[16 * 1024];    // 64 KB staged h_prev tile (rotated rows)

  const int bid = blockIdx.x;
  const int tid = threadIdx.x;
  const int xcd = bid & 7;
  const int u = bid >> 3;             // 0..31
  const int bg = u >> 3;              // 0..3
  const int hg = xcd * 8 + (u & 7);   // 0..63  (XCD-major)
  const int b0 = bg * 16;

  const int lane = tid & 63;
  const int khalf = lane >> 5;                       // 0/1: K half
  const int pid = ((tid >> 6) << 5) | (lane & 31);   // 0..255
  const int b_l = pid >> 4;                          // 0..15
  const int hcl = pid & 15;                          // 0..15
  const int b = b0 + b_l;
  const int hc = hg * 16 + hcl;

  const float4* w40 = reinterpret_cast<const float4*>(Whh + ((size_t)(0 * Hn + hc)) * Hn + khalf * 512);
  const float4* w41 = reinterpret_cast<const float4*>(Whh + ((size_t)(1 * Hn + hc)) * Hn + khalf * 512);
  const float4* w42 = reinterpret_cast<const float4*>(Whh + ((size_t)(2 * Hn + hc)) * Hn + khalf * 512);
  const float4* w43 = reinterpret_cast<const float4*>(Whh + ((size_t)(3 * Hn + hc)) * Hn + khalf * 512);

  const int* xrow = x + (size_t)b * Tn;
  unsigned long long* mybar = bar + (size_t)bg * 16;   // 128 B apart
  const float4* hrow4 = reinterpret_cast<const float4*>(hsm + b_l * 1024);
  const int rotbase = khalf * 128 + b_l;               // float4-granular rotation

  float cst = 0.f;

  for (int t = 0; t < Tn; ++t) {
    const int cls = xrow[t];
    const float* pr = proj + (size_t)cls * Gn + hc;
    float a0 = pr[0], a1 = pr[Hn], a2 = pr[2 * Hn], a3 = pr[3 * Hn];

    if (t > 0) {
      // stage h[t-1] tile: cache-bypassing loads (cross-XCD safe), rotated rows
      #pragma unroll
      for (int i = 0; i < 32; ++i) {
        int f = tid + (i << 9);
        int row = f >> 10, col = f & 1023;
        float v = __hip_atomic_load(
            hs + ((size_t)(b0 + row) * Tn + (t - 1)) * (size_t)Hn + col,
            __ATOMIC_RELAXED, __HIP_MEMORY_SCOPE_AGENT);
        hsm[row * 1024 + ((col + row * 4) & 1023)] = v;
      }
      __syncthreads();

      float s0 = 0.f, s1 = 0.f, s2 = 0.f, s3 = 0.f;
      #pragma unroll 2
      for (int k = 0; k < 128; ++k) {
        float4 hv = hrow4[(rotbase + k) & 255];
        float4 w0 = w40[k], w1 = w41[k], w2 = w42[k], w3 = w43[k];
        s0 += hv.x * w0.x + hv.y * w0.y + hv.z * w0.z + hv.w * w0.w;
        s1 += hv.x * w1.x + hv.y * w1.y + hv.z * w1.z + hv.w * w1.w;
        s2 += hv.x * w2.x + hv.y * w2.y + hv.z * w2.z + hv.w * w2.w;
        s3 += hv.x * w3.x + hv.y * w3.y + hv.z * w3.z + hv.w * w3.w;
      }
      // combine the two K-halves (partner lane = lane^32)
      a0 += s0 + __shfl_xor(s0, 32);
      a1 += s1 + __shfl_xor(s1, 32);
      a2 += s2 + __shfl_xor(s2, 32);
      a3 += s3 + __shfl_xor(s3, 32);
    }

    float ig = sigmoidf_(a0);
    float fg = sigmoidf_(a1);
    float gg = tanhf(a2);
    float og = sigmoidf_(a3);
    cst = fg * cst + ig * gg;
    float hv_ = og * tanhf(cst);

    if (khalf == 0) {
      // write-through so every XCD's readers see it next step
      __hip_atomic_store(hs + ((size_t)b * Tn + t) * (size_t)Hn + hc, hv_,
                         __ATOMIC_RELAXED, __HIP_MEMORY_SCOPE_AGENT);
    }
    grid_sync(mybar, 64);
  }
}

// ---------------------------------------------------------------------------
extern "C" void kernel_launch(void* const* d_in, const int* in_sizes, int n_in,
                              void* d_out, int out_size, void* d_ws, size_t ws_size,
                              hipStream_t stream) {
  const int*   x     = (const int*)  d_in[0];
  const float* embed = (const float*)d_in[1];
  const float* Wih   = (const float*)d_in[2];
  const float* Whh   = (const float*)d_in[3];
  const float* bih   = (const float*)d_in[4];
  const float* bhh   = (const float*)d_in[5];
  const float* fcW   = (const float*)d_in[6];
  const float* fcb   = (const float*)d_in[7];
  float* out = (float*)d_out;

  char* ws = (char*)d_ws;
  const size_t projBytes = (size_t)Cn * Gn * sizeof(float);          // 4 MB
  const size_t hsBytes   = (size_t)Bn * Tn * Hn * sizeof(float);     // 128 MB
  const size_t need = 1024 + projBytes + hsBytes;
  if (ws_size < need) {  // fail visibly rather than scribble OOB
    hipMemsetAsync(d_out, 0, (size_t)out_size * sizeof(float), stream);
    return;
  }
  float* proj = (float*)(ws + 1024);
  float* hs   = (float*)(ws + 1024 + projBytes);

  // zero barrier area every call (ws is poisoned once, never re-poisoned)
  hipMemsetAsync(d_ws, 0, 1024, stream);

  // 1) proj[cls, 4H] = embed[cls,:] @ W_ih^T + b_ih + b_hh
  dim3 g1(Cn / 64, Gn / 64);   // (4, 64)
  gemm_tt<<<g1, 256, 0, stream>>>(embed, Wih, bih, bhh, proj, Cn, Gn, En);

  // 2) persistent recurrence
  lstm_persistent<<<256, 512, 0, stream>>>(x, Whh, proj, hs,
                                           (unsigned long long*)d_ws);

  // 3) out[b*T+t, c] = hs[b,t,:] @ fc_W^T + fc_b
  dim3 g3((Bn * Tn) / 64, Cn / 64);  // (512, 4)
  gemm_tt<<<g3, 256, 0, stream>>>(hs, fcW, fcb, nullptr, out, Bn * Tn, Cn, Hn);
}

// Round 2
// 45158.658 us; speedup vs baseline: 1.4127x; 1.4127x over previous
//
#include <hip/hip_runtime.h>
#include <math.h>

#define DEV_INLINE __device__ __forceinline__

static constexpr int Bn = 64;     // batch
static constexpr int Tn = 512;    // time
static constexpr int En = 512;    // embed
static constexpr int Hn = 1024;   // hidden
static constexpr int Cn = 256;    // classes
static constexpr int Gn = 4 * Hn; // 4096 gates

typedef float v4f __attribute__((ext_vector_type(4)));
typedef unsigned long long ull;

DEV_INLINE float sigmoidf_(float v) { return 1.f / (1.f + __expf(-v)); }

// ---------------------------------------------------------------------------
// Generic fp32 tiled GEMM:  C[M,N] = A[M,K] * B[N,K]^T + bias1[n] (+bias2[n])
// ---------------------------------------------------------------------------
__global__ __launch_bounds__(256) void gemm_tt(
    const float* __restrict__ A, const float* __restrict__ Bm,
    const float* __restrict__ bias1, const float* __restrict__ bias2,
    float* __restrict__ Cm, int M, int N, int K)
{
  constexpr int KC = 32;
  __shared__ float As[KC][68];
  __shared__ float Bs[KC][68];
  const int tid = threadIdx.x;
  const int tx = tid & 15, ty = tid >> 4;
  const int m0 = blockIdx.x * 64, n0 = blockIdx.y * 64;

  float acc[4][4] = {};

  for (int k0 = 0; k0 < K; k0 += KC) {
    __syncthreads();
    #pragma unroll
    for (int j = 0; j < 2; ++j) {
      int f = tid + j * 256;
      int row = f >> 3;
      int c4 = f & 7;
      float4 va = *reinterpret_cast<const float4*>(&A[(size_t)(m0 + row) * K + k0 + c4 * 4]);
      As[c4 * 4 + 0][row] = va.x; As[c4 * 4 + 1][row] = va.y;
      As[c4 * 4 + 2][row] = va.z; As[c4 * 4 + 3][row] = va.w;
      float4 vb = *reinterpret_cast<const float4*>(&Bm[(size_t)(n0 + row) * K + k0 + c4 * 4]);
      Bs[c4 * 4 + 0][row] = vb.x; Bs[c4 * 4 + 1][row] = vb.y;
      Bs[c4 * 4 + 2][row] = vb.z; Bs[c4 * 4 + 3][row] = vb.w;
    }
    __syncthreads();
    #pragma unroll
    for (int k = 0; k < KC; ++k) {
      float4 a4 = *reinterpret_cast<const float4*>(&As[k][ty * 4]);
      float4 b4 = *reinterpret_cast<const float4*>(&Bs[k][tx * 4]);
      float ar[4] = {a4.x, a4.y, a4.z, a4.w};
      float br[4] = {b4.x, b4.y, b4.z, b4.w};
      #pragma unroll
      for (int i = 0; i < 4; ++i)
        #pragma unroll
        for (int j = 0; j < 4; ++j)
          acc[i][j] += ar[i] * br[j];
    }
  }

  #pragma unroll
  for (int j = 0; j < 4; ++j) {
    int n = n0 + tx * 4 + j;
    float bb = bias1[n];
    if (bias2) bb += bias2[n];
    #pragma unroll
    for (int i = 0; i < 4; ++i)
      Cm[(size_t)(m0 + ty * 4 + i) * N + n] = acc[i][j] + bb;
  }
}

// ---------------------------------------------------------------------------
// W-stationary persistent LSTM. 256 blocks x 512 threads (1 block/CU).
// Block (bg 0..3, hg 0..63): batch rows [bg*16,+16), h-cols [hg*16,+16).
// Thread: wave w (0..7), hcm = lane&1, ks = lane>>1 (32-way K split).
//   Owns W rows (4 gates) of hc = hg*16 + w*2 + hcm, K range [ks*32,+32),
//   held in 32 float4 REGISTERS for the whole kernel.
// Per step: stage h[t-1] tile (64KB) global->LDS, 2048 reg-resident FMAs,
// log2(32) reduce-scatter over shfl_xor, elementwise on 256 threads,
// flag-based (no atomic contention) 64-block barrier per batch group.
// ---------------------------------------------------------------------------

// 16 fused FMAs per (b,j): one LDS float4 feeds 4 gate rows held in regs.
#define FG_(b,g,j,H) a[(g)*16+(b)] = __builtin_fmaf((H).w, wv[g][j].w, \
    __builtin_fmaf((H).z, wv[g][j].z, __builtin_fmaf((H).y, wv[g][j].y, \
    __builtin_fmaf((H).x, wv[g][j].x, a[(g)*16+(b)]))));
#define JS_(b,j) { v4f Hv = hsm4[(b)*256 + jidx[j]]; \
  FG_(b,0,j,Hv) FG_(b,1,j,Hv) FG_(b,2,j,Hv) FG_(b,3,j,Hv) }
#define ROW_(b) JS_(b,0) JS_(b,1) JS_(b,2) JS_(b,3) JS_(b,4) JS_(b,5) JS_(b,6) JS_(b,7)
#define KLOOP ROW_(0) ROW_(1) ROW_(2) ROW_(3) ROW_(4) ROW_(5) ROW_(6) ROW_(7) \
              ROW_(8) ROW_(9) ROW_(10) ROW_(11) ROW_(12) ROW_(13) ROW_(14) ROW_(15)

#define RROUND(L, MASK, BIT) \
  _Pragma("unroll") \
  for (int j2 = 0; j2 < (L); ++j2) { \
    float snd = (BIT) ? a[j2] : a[j2 + (L)]; \
    float kp  = (BIT) ? a[j2 + (L)] : a[j2]; \
    a[j2] = kp + __shfl_xor(snd, (MASK)); \
  }

__global__ __launch_bounds__(512, 2) void lstm_persistent(
    const int* __restrict__ x,        // [B, T]
    const float* __restrict__ Whh,    // [4H, H]
    const float* __restrict__ proj,   // [C, 4H] class gates incl. both biases
    float* __restrict__ hs,           // [B, T, H]
    int* __restrict__ flags)          // [4][64] gen counters, 128B apart
{
  __shared__ __align__(16) float hsm[16 * 1024];   // 64 KB staged h tile
  float* gbufF = hsm;            // gate exchange buffer aliases hsm[0..1023]

  const int tid = threadIdx.x;
  const int bid = blockIdx.x;
  const int bg = bid >> 6;       // 0..3
  const int hg = bid & 63;       // 0..63
  const int b0 = bg * 16;

  const int w_ = tid >> 6;       // wave 0..7
  const int lane = tid & 63;
  const int hcm = lane & 1;
  const int ks = lane >> 1;      // 0..31 K-split
  const int hc_l = w_ * 2 + hcm; // 0..15
  const int hc = hg * 16 + hc_l;

  // ---- one-time W preload into registers (rotated to match h read order)
  v4f wv[4][8];
  #pragma unroll
  for (int g = 0; g < 4; ++g) {
    const float* wb = Whh + ((size_t)(g * 1024 + hc)) * 1024 + ks * 32;
    #pragma unroll
    for (int j = 0; j < 8; ++j)
      wv[g][j] = *(const v4f*)(wb + ((ks + j) & 7) * 4);
  }
  int jidx[8];
  #pragma unroll
  for (int j = 0; j < 8; ++j) jidx[j] = ks * 8 + ((ks + j) & 7);

  const v4f* hsm4 = (const v4f*)hsm;
  ull* hsm8 = (ull*)hsm;

  const int ew = (tid < 256);
  const int b_l = tid >> 4, hcl = tid & 15;        // elementwise mapping
  const int* xp = x + (size_t)(b0 + b_l) * Tn;
  float cst = 0.f;

  int* myflag = flags + (size_t)(bg * 64 + hg) * 32;
  const int* pollbase = flags + (size_t)(bg * 64) * 32;

  // final element ids after reduce-scatter (bit-reversed ks)
  const int e0 = ((ks & 1) << 5) | (((ks >> 1) & 1) << 4) | (((ks >> 2) & 1) << 3)
               | (((ks >> 3) & 1) << 2) | (((ks >> 4) & 1) << 1);
  const int e1 = e0 | 1;

  for (int t = 0; t < Tn; ++t) {
    // prefetch class projection (independent of h -> hides under staging/FMA)
    float p0 = 0.f, p1 = 0.f, p2 = 0.f, p3 = 0.f;
    if (ew) {
      int cls = xp[t];
      const float* pb = proj + (size_t)cls * Gn + hg * 16 + hcl;
      p0 = pb[0]; p1 = pb[Hn]; p2 = pb[2 * Hn]; p3 = pb[3 * Hn];
    }

    // stage h[t-1] tile: 8B agent-scope loads (cross-XCD safe), then LDS
    if (t > 0) {
      ull stg[16];
      #pragma unroll
      for (int i = 0; i < 16; ++i) {
        const ull* sp = (const ull*)hs + ((size_t)(b0 + i) * Tn + (t - 1)) * 512 + tid;
        stg[i] = __hip_atomic_load(sp, __ATOMIC_RELAXED, __HIP_MEMORY_SCOPE_AGENT);
      }
      #pragma unroll
      for (int i = 0; i < 16; ++i) hsm8[i * 512 + tid] = stg[i];
    }
    __syncthreads();

    float a[64];
    #pragma unroll
    for (int i = 0; i < 64; ++i) a[i] = 0.f;

    if (t > 0) { KLOOP }

    // reduce-scatter over the 32 ks lanes: 62 shuffles total
    RROUND(32, 2, (ks & 1))
    RROUND(16, 4, ((ks >> 1) & 1))
    RROUND(8, 8, ((ks >> 2) & 1))
    RROUND(4, 16, ((ks >> 3) & 1))
    RROUND(2, 32, ((ks >> 4) & 1))

    __syncthreads();   // hsm reads done before gbuf (aliased) writes
    gbufF[(e0 & 15) * 64 + (e0 >> 4) * 16 + hc_l] = a[0];
    gbufF[(e1 & 15) * 64 + (e1 >> 4) * 16 + hc_l] = a[1];
    __syncthreads();

    if (ew) {
      float g0 = gbufF[b_l * 64 +  0 + hcl] + p0;
      float g1 = gbufF[b_l * 64 + 16 + hcl] + p1;
      float g2 = gbufF[b_l * 64 + 32 + hcl] + p2;
      float g3 = gbufF[b_l * 64 + 48 + hcl] + p3;
      float ig = sigmoidf_(g0), fg = sigmoidf_(g1);
      float gg = tanhf(g2),     og = sigmoidf_(g3);
      cst = fg * cst + ig * gg;
      float hv = og * tanhf(cst);
      __hip_atomic_store(hs + ((size_t)(b0 + b_l) * Tn + t) * Hn + hg * 16 + hcl,
                         hv, __ATOMIC_RELAXED, __HIP_MEMORY_SCOPE_AGENT);
    }

    if (t + 1 < Tn) {
      __syncthreads();   // all h stores drained (vmcnt) before flag store
      if (tid == 0)
        __hip_atomic_store(myflag, t + 1, __ATOMIC_RELAXED, __HIP_MEMORY_SCOPE_AGENT);
      if (tid < 64) {
        const int* fp = pollbase + (size_t)tid * 32;
        while (__hip_atomic_load(fp, __ATOMIC_RELAXED, __HIP_MEMORY_SCOPE_AGENT) <= t)
          __builtin_amdgcn_s_sleep(2);
      }
      __syncthreads();
    }
  }
}

// ---------------------------------------------------------------------------
extern "C" void kernel_launch(void* const* d_in, const int* in_sizes, int n_in,
                              void* d_out, int out_size, void* d_ws, size_t ws_size,
                              hipStream_t stream) {
  const int*   x     = (const int*)  d_in[0];
  const float* embed = (const float*)d_in[1];
  const float* Wih   = (const float*)d_in[2];
  const float* Whh   = (const float*)d_in[3];
  const float* bih   = (const float*)d_in[4];
  const float* bhh   = (const float*)d_in[5];
  const float* fcW   = (const float*)d_in[6];
  const float* fcb   = (const float*)d_in[7];
  float* out = (float*)d_out;

  char* ws = (char*)d_ws;
  const size_t flagBytes = 32768;                                    // 4*64 flags, 128B apart
  const size_t projBytes = (size_t)Cn * Gn * sizeof(float);          // 4 MB
  const size_t hsBytes   = (size_t)Bn * Tn * Hn * sizeof(float);     // 128 MB
  const size_t need = flagBytes + projBytes + hsBytes;
  if (ws_size < need) {  // fail visibly rather than scribble OOB
    hipMemsetAsync(d_out, 0, (size_t)out_size * sizeof(float), stream);
    return;
  }
  float* proj = (float*)(ws + flagBytes);
  float* hs   = (float*)(ws + flagBytes + projBytes);

  // zero barrier flags every call (graph-capture-safe async memset)
  hipMemsetAsync(d_ws, 0, flagBytes, stream);

  // 1) proj[cls, 4H] = embed[cls,:] @ W_ih^T + b_ih + b_hh
  dim3 g1(Cn / 64, Gn / 64);   // (4, 64)
  gemm_tt<<<g1, 256, 0, stream>>>(embed, Wih, bih, bhh, proj, Cn, Gn, En);

  // 2) W-stationary persistent recurrence
  lstm_persistent<<<256, 512, 0, stream>>>(x, Whh, proj, hs, (int*)d_ws);

  // 3) out[b*T+t, c] = hs[b,t,:] @ fc_W^T + fc_b
  dim3 g3((Bn * Tn) / 64, Cn / 64);  // (512, 4)
  gemm_tt<<<g3, 256, 0, stream>>>(hs, fcW, fcb, nullptr, out, Bn * Tn, Cn, Hn);
}